// Round 3
// baseline (240.785 us; speedup 1.0000x reference)
//
#include <hip/hip_runtime.h>
#include <hip/hip_bf16.h>

// Fused quantized conv chain, integer-scaled domain:
//   X = 128*fake_quant(x) in [-128,127] (integer-valued floats)
//   Y = clamp(floor(128*b1q + 0.5 + sum X*w1q), -128, 127)      (= 128*y_q)
//   Z = clamp(floor(128*b2q + 0.5 + sum Y*w2q), -128, 127)      (= 128*z_q)
//   out = Z * (1/128)
// All intermediates are exact multiples of 1/128 bounded << 2^17, so fp32
// arithmetic is exact and matches the reference bit-for-bit.

#define T 8  // output positions per thread

__device__ __forceinline__ float q128(float v) {
    // clamp(floor(v*128 + 0.5), -128, 127) -- integer-valued float
    float t = floorf(fmaf(v, 128.0f, 0.5f));
    return fminf(fmaxf(t, -128.0f), 127.0f);   // -> v_med3_f32
}

__device__ __forceinline__ float fq8(float v) { return q128(v) * 0.0078125f; }

__global__ __launch_bounds__(256) void fused_qconv_kernel(
    const float* __restrict__ x,
    const float* __restrict__ w1, const float* __restrict__ b1,
    const float* __restrict__ gamma, const float* __restrict__ beta,
    const float* __restrict__ bn_mean, const float* __restrict__ bn_var,
    const float* __restrict__ w2, const float* __restrict__ b2,
    float* __restrict__ out,
    int L, int chunksPerRow)
{
    // ---- per-channel weight row: [0..11]=w1q, [12]=128*b1q+0.5,
    //      [13..15]=w2q[o=0][c][k], [16..18]=w2q[o=1][c][k], [19]=pad ----
    __shared__ float s_cw[8][20];   // 80 B/row, 16B-aligned rows
    __shared__ float s_b2[2];

    const int t = threadIdx.x;
    if (t < 162) {
        if (t < 160) {
            const int c = t / 20, j = t - c * 20;
            float v;
            if (j < 12) {
                float sf = gamma[c] * (1.0f / sqrtf(bn_var[c] + 1e-5f));
                v = fq8(w1[c * 12 + j] * sf);
            } else if (j == 12) {
                float sf = gamma[c] * (1.0f / sqrtf(bn_var[c] + 1e-5f));
                v = fmaf(fq8((b1[c] - bn_mean[c]) * sf + beta[c]), 128.0f, 0.5f);
            } else if (j < 16) {
                v = fq8(w2[c * 3 + (j - 13)]);          // o=0
            } else if (j < 19) {
                v = fq8(w2[24 + c * 3 + (j - 16)]);     // o=1
            } else {
                v = 0.0f;
            }
            s_cw[c][j] = v;
        } else {
            s_b2[t - 160] = fmaf(fq8(b2[t - 160]), 128.0f, 0.5f);
        }
    }
    __syncthreads();

    const int pc = blockIdx.x * blockDim.x + t;   // chunk within row
    if (pc >= chunksPerRow) return;
    const int n = blockIdx.y;
    const int pos0 = pc * T;
    const bool le = (pos0 == 0);
    const bool re = (pos0 + T == L);

    // ---- load + quantize x window: positions pos0-2 .. pos0+9, all float4 ----
    float X[4][12];
    const float* xb = x + (size_t)(n * 4) * (size_t)L + (unsigned)pos0;
#pragma unroll
    for (int i = 0; i < 4; ++i) {
        const float* xr = xb + (unsigned)(i * L);
        float4 a = *(const float4*)(xr);       // pos0..pos0+3
        float4 b = *(const float4*)(xr + 4);   // pos0+4..pos0+7
        X[i][2] = q128(a.x); X[i][3] = q128(a.y); X[i][4] = q128(a.z); X[i][5] = q128(a.w);
        X[i][6] = q128(b.x); X[i][7] = q128(b.y); X[i][8] = q128(b.z); X[i][9] = q128(b.w);
        if (!le) {
            float4 h = *(const float4*)(xr - 4);   // pos0-4..pos0-1
            X[i][0] = q128(h.z); X[i][1] = q128(h.w);
        } else { X[i][0] = 0.0f; X[i][1] = 0.0f; }
        if (!re) {
            float4 h = *(const float4*)(xr + 8);   // pos0+8..pos0+11
            X[i][10] = q128(h.x); X[i][11] = q128(h.y);
        } else { X[i][10] = 0.0f; X[i][11] = 0.0f; }
    }

    // ---- conv2 accumulators (scaled domain): init = 128*b2q + 0.5 ----
    float acc[2][T];
    {
        const float a0 = s_b2[0], a1 = s_b2[1];
#pragma unroll
        for (int j = 0; j < T; ++j) { acc[0][j] = a0; acc[1][j] = a1; }
    }

#pragma unroll
    for (int c = 0; c < 8; ++c) {
        const float4 cw0 = *(const float4*)&s_cw[c][0];
        const float4 cw1 = *(const float4*)&s_cw[c][4];
        const float4 cw2 = *(const float4*)&s_cw[c][8];
        const float4 cw3 = *(const float4*)&s_cw[c][12];
        const float4 cw4 = *(const float4*)&s_cw[c][16];
        const float w00 = cw0.x, w01 = cw0.y, w02 = cw0.z;
        const float w10 = cw0.w, w11 = cw1.x, w12 = cw1.y;
        const float w20 = cw1.z, w21 = cw1.w, w22 = cw2.x;
        const float w30 = cw2.y, w31 = cw2.z, w32 = cw2.w;
        const float bc  = cw3.x;                       // 128*b1q + 0.5
        const float u0 = cw3.y, u1 = cw3.z, u2 = cw3.w; // w2q[0][c][0..2]
        const float v0 = cw4.x, v1 = cw4.y, v2 = cw4.z; // w2q[1][c][0..2]

        // y positions l' = pos0-1+p, p in [0, 10)
#pragma unroll
        for (int p = 0; p < T + 2; ++p) {
            float v = bc;
            v = fmaf(X[0][p], w00, v); v = fmaf(X[0][p + 1], w01, v); v = fmaf(X[0][p + 2], w02, v);
            v = fmaf(X[1][p], w10, v); v = fmaf(X[1][p + 1], w11, v); v = fmaf(X[1][p + 2], w12, v);
            v = fmaf(X[2][p], w20, v); v = fmaf(X[2][p + 1], w21, v); v = fmaf(X[2][p + 2], w22, v);
            v = fmaf(X[3][p], w30, v); v = fmaf(X[3][p + 1], w31, v); v = fmaf(X[3][p + 2], w32, v);
            float Y = fminf(fmaxf(floorf(v), -128.0f), 127.0f);   // 128*y_q
            if (p == 0     && le) Y = 0.0f;   // conv2 sees padding zero at y[-1]
            if (p == T + 1 && re) Y = 0.0f;   // ... and at y[L]
            // scatter: z[l'+1-k] += Y * w2q[k]
            if (p < T) {
                acc[0][p] = fmaf(Y, u0, acc[0][p]);
                acc[1][p] = fmaf(Y, v0, acc[1][p]);
            }
            if (p >= 1 && p - 1 < T) {
                acc[0][p - 1] = fmaf(Y, u1, acc[0][p - 1]);
                acc[1][p - 1] = fmaf(Y, v1, acc[1][p - 1]);
            }
            if (p >= 2) {
                acc[0][p - 2] = fmaf(Y, u2, acc[0][p - 2]);
                acc[1][p - 2] = fmaf(Y, v2, acc[1][p - 2]);
            }
        }
    }

    // ---- final quantize (floor+clamp only) + scale-back + vectorized store ----
    float* ob = out + (size_t)(n * 2) * (size_t)L + (unsigned)pos0;
#pragma unroll
    for (int o = 0; o < 2; ++o) {
        float4 r0, r1;
        r0.x = fminf(fmaxf(floorf(acc[o][0]), -128.0f), 127.0f) * 0.0078125f;
        r0.y = fminf(fmaxf(floorf(acc[o][1]), -128.0f), 127.0f) * 0.0078125f;
        r0.z = fminf(fmaxf(floorf(acc[o][2]), -128.0f), 127.0f) * 0.0078125f;
        r0.w = fminf(fmaxf(floorf(acc[o][3]), -128.0f), 127.0f) * 0.0078125f;
        r1.x = fminf(fmaxf(floorf(acc[o][4]), -128.0f), 127.0f) * 0.0078125f;
        r1.y = fminf(fmaxf(floorf(acc[o][5]), -128.0f), 127.0f) * 0.0078125f;
        r1.z = fminf(fmaxf(floorf(acc[o][6]), -128.0f), 127.0f) * 0.0078125f;
        r1.w = fminf(fmaxf(floorf(acc[o][7]), -128.0f), 127.0f) * 0.0078125f;
        *(float4*)(ob + (size_t)o * (size_t)L)     = r0;
        *(float4*)(ob + (size_t)o * (size_t)L + 4) = r1;
    }
}

extern "C" void kernel_launch(void* const* d_in, const int* in_sizes, int n_in,
                              void* d_out, int out_size, void* d_ws, size_t ws_size,
                              hipStream_t stream) {
    const float* x       = (const float*)d_in[0];
    const float* w1      = (const float*)d_in[1];
    const float* b1      = (const float*)d_in[2];
    const float* gamma   = (const float*)d_in[3];
    const float* beta    = (const float*)d_in[4];
    const float* bn_mean = (const float*)d_in[5];
    const float* bn_var  = (const float*)d_in[6];
    const float* w2      = (const float*)d_in[7];
    const float* b2      = (const float*)d_in[8];
    float* out = (float*)d_out;

    const int B = 16;
    const int L = in_sizes[0] / (B * 4);        // 524288
    const int chunksPerRow = L / T;             // 65536
    const int block = 256;
    const int gridX = (chunksPerRow + block - 1) / block;  // 256

    fused_qconv_kernel<<<dim3(gridX, B), block, 0, stream>>>(
        x, w1, b1, gamma, beta, bn_mean, bn_var, w2, b2, out,
        L, chunksPerRow);
}